// Round 20
// baseline (1693.617 us; speedup 1.0000x reference)
//
#include <hip/hip_runtime.h>
#include <hip/hip_bf16.h>
#include <float.h>

#define NPTS 4096
#define NB 4
#define KNN 20

__device__ __forceinline__ float lrelu(float x) { return x > 0.f ? x : 0.2f * x; }

__device__ __forceinline__ void atomicMaxF(float* addr, float val) {
    int* ia = (int*)addr;
    int old = *ia;
    while (__int_as_float(old) < val) {
        int assumed = old;
        old = atomicCAS(ia, assumed, __float_as_int(val));
        if (old == assumed) break;
    }
}

// ---------------- generic transpose: dst[c][r] = src[r][c0..] ----------------
__global__ void k_transp(const float* __restrict__ src, float* __restrict__ dst,
                         int rows, int srcld, int cols) {
    int i = blockIdx.x * 256 + threadIdx.x;
    if (i >= rows * cols) return;
    int r = i % rows, c = i / rows;              // writes coalesced
    dst[c * rows + r] = src[(size_t)r * srcld + c];
}

// ---------------- sq norms for euclid knn ----------------
__global__ void k_sqnorm(const float* __restrict__ x, float* __restrict__ sq) {
    int i = blockIdx.x * 256 + threadIdx.x;   // b*N + n
    int b = i >> 12, n = i & 4095;
    const float* xb = x + b * 6 * NPTS;
    float s = 0.f;
#pragma unroll
    for (int c = 0; c < 6; c++) { float v = xb[c * NPTS + n]; s += v * v; }
    sq[i] = s;
}

// ---------------- euclid knn v3: streaming ballot top-20 on sv=-d, no LDS ----------------
__global__ __launch_bounds__(256) void k_knn_euclid(const float* __restrict__ x,
                                                    const float* __restrict__ sq,
                                                    int* __restrict__ idx) {
    int t = threadIdx.x;
    int w = t >> 6, ln = t & 63;
    int qid = blockIdx.x * 4 + w;
    int b = qid >> 12, qn = qid & 4095;
    const float* xb = x + b * 6 * NPTS;
    const float* sqb = sq + b * NPTS;
    float q0 = xb[qn], q1 = xb[NPTS + qn], q2 = xb[2 * NPTS + qn];
    float q3 = xb[3 * NPTS + qn], q4 = xb[4 * NPTS + qn], q5 = xb[5 * NPTS + qn];
    float sqn = sqb[qn];
    float lv = -FLT_MAX; int li = 0x7fffffff;
    float th = -FLT_MAX;
    for (int t0 = 0; t0 < NPTS; t0 += 64) {
        int m = t0 + ln;
        float dot = q0 * xb[m] + q1 * xb[NPTS + m] + q2 * xb[2 * NPTS + m]
                  + q3 * xb[3 * NPTS + m] + q4 * xb[4 * NPTS + m] + q5 * xb[5 * NPTS + m];
        float sv = -(sqn - 2.f * dot + sqb[m]);      // top-k of -d, exactly as reference
        unsigned long long mask = __ballot(sv > th);
        while (mask) {
            int src = __ffsll((unsigned long long)mask) - 1;
            mask &= mask - 1;
            float v = __shfl(sv, src);
            if (!(v > th)) continue;
            int mi = t0 + src;
            float pv = __shfl_up(lv, 1);
            int   pi = __shfl_up(li, 1);
            unsigned long long bm = __ballot(ln < 20 && lv >= v);
            int pos = __popcll(bm);
            if (ln < 20) {
                if (ln == pos) { lv = v; li = mi; }
                else if (ln > pos) { lv = pv; li = pi; }
            }
            th = __shfl(lv, 19);
        }
    }
    if (ln < KNN) idx[qid * KNN + ln] = li;
}

// ---------------- cosine knn v16b: 8 queries/block (2/wave), fixed batch decode ----------------
// 2048 blocks total = 512 blocks/batch = 8 blocks/CU = 8 waves/SIMD (chain TLP x2).
// Verified ballot-insertion logic verbatim.
__global__ __launch_bounds__(256) void k_knn_cos(const float* __restrict__ xn,
                                                 const float* __restrict__ xnT,
                                                 int* __restrict__ idx) {
    __shared__ float xq[64][12];         // [ch][q], 8 used (3.1 KB)
    __shared__ float simb[8][520];       // wave-private rows q=2w..2w+1 (16.6 KB)
    int t = threadIdx.x;
    int w = t >> 6, ln = t & 63;
    int b = blockIdx.x >> 9;             // 512 blocks per batch
    int q0blk = (blockIdx.x & 511) * 8;
    const float* xqg = xn + ((size_t)(b << 12) + q0blk) * 64;
    // stage 8 queries, transpose to [ch][q]
    if (t < 128) {
        int q = t >> 4, c4 = t & 15;     // 128 float4
        float4 v = *(const float4*)(xqg + q * 64 + c4 * 4);
        xq[c4 * 4 + 0][q] = v.x; xq[c4 * 4 + 1][q] = v.y;
        xq[c4 * 4 + 2][q] = v.z; xq[c4 * 4 + 3][q] = v.w;
    }
    __syncthreads();
    int myq = w * 2;
    const float* xTb = xnT + (((size_t)b) << 12) * 64;  // [c][4096]
    float lv[2] = {-FLT_MAX, -FLT_MAX};
    int   li[2] = {0x7fffffff, 0x7fffffff};
    float th[2] = {-FLT_MAX, -FLT_MAX};
    for (int strip = 0; strip < 8; strip++) {
        int m0 = strip * 512 + ln * 8;   // this lane's 8 candidates
        float4 a0[2], a1[2];
#pragma unroll
        for (int q = 0; q < 2; q++) { a0[q] = (float4){0,0,0,0}; a1[q] = (float4){0,0,0,0}; }
        for (int c = 0; c < 64; c++) {
            const float* cr = xTb + (((size_t)c) << 12) + m0;
            float4 cv0 = *(const float4*)(cr);
            float4 cv1 = *(const float4*)(cr + 4);
            float2 qv = *(const float2*)&xq[c][myq];   // wave-uniform broadcast
            a0[0].x += qv.x * cv0.x; a0[0].y += qv.x * cv0.y; a0[0].z += qv.x * cv0.z; a0[0].w += qv.x * cv0.w;
            a1[0].x += qv.x * cv1.x; a1[0].y += qv.x * cv1.y; a1[0].z += qv.x * cv1.z; a1[0].w += qv.x * cv1.w;
            a0[1].x += qv.y * cv0.x; a0[1].y += qv.y * cv0.y; a0[1].z += qv.y * cv0.z; a0[1].w += qv.y * cv0.w;
            a1[1].x += qv.y * cv1.x; a1[1].y += qv.y * cv1.y; a1[1].z += qv.y * cv1.z; a1[1].w += qv.y * cv1.w;
        }
        // per query: group pre-filter, conditional dump, filtered insertion passes
#pragma unroll
        for (int q = 0; q < 2; q++) {
            float mx8 = fmaxf(fmaxf(fmaxf(a0[q].x, a0[q].y), fmaxf(a0[q].z, a0[q].w)),
                              fmaxf(fmaxf(a1[q].x, a1[q].y), fmaxf(a1[q].z, a1[q].w)));
            unsigned long long gmask = __ballot(mx8 > th[q]);
            if (!gmask) continue;        // whole strip empty for this query
            *(float4*)&simb[myq + q][ln * 8] = a0[q];
            *(float4*)&simb[myq + q][ln * 8 + 4] = a1[q];
            for (int j = 0; j < 8; j++) {
                if (!((gmask >> (8 * j)) & 0xffull)) continue;   // group provably empty
                float sv = simb[myq + q][j * 64 + ln];
                int base = strip * 512 + j * 64;
                unsigned long long mask = __ballot(sv > th[q]);
                while (mask) {
                    int src = __ffsll((unsigned long long)mask) - 1;
                    mask &= mask - 1;
                    float v = __shfl(sv, src);
                    if (!(v > th[q])) continue;
                    int mi = base + src;
                    float pv = __shfl_up(lv[q], 1);
                    int   pi = __shfl_up(li[q], 1);
                    unsigned long long bm = __ballot(ln < 20 && lv[q] >= v);
                    int pos = __popcll(bm);
                    if (ln < 20) {
                        if (ln == pos) { lv[q] = v; li[q] = mi; }
                        else if (ln > pos) { lv[q] = pv; li[q] = pi; }
                    }
                    th[q] = __shfl(lv[q], 19);
                }
            }
        }
    }
#pragma unroll
    for (int q = 0; q < 2; q++) {
        if (ln < KNN) {
            int qid = (b << 12) + q0blk + myq + q;
            idx[(size_t)qid * KNN + ln] = li[q];
        }
    }
}

// ---------------- normalize 64 cols of point-major xcpm -> xn (point-major) + xnT (channel-major)
__global__ void k_normalize(const float* __restrict__ xcpm, int coff,
                            float* __restrict__ xn, float* __restrict__ xnT) {
    int pid = blockIdx.x * 256 + threadIdx.x;
    int b = pid >> 12, n = pid & 4095;
    const float* p = xcpm + (size_t)pid * 192 + coff;
    float s = 0.f;
#pragma unroll
    for (int c4 = 0; c4 < 16; c4++) {
        float4 v = *(const float4*)(p + c4 * 4);
        s += v.x * v.x + v.y * v.y + v.z * v.z + v.w * v.w;
    }
    float inv = 1.f / (sqrtf(s) + 1e-8f);
    float* q = xn + (size_t)pid * 64;
    float* qt = xnT + (((size_t)b) << 12) * 64 + n;
#pragma unroll
    for (int c4 = 0; c4 < 16; c4++) {
        float4 v = *(const float4*)(p + c4 * 4);
        float4 r; r.x = v.x * inv; r.y = v.y * inv; r.z = v.z * inv; r.w = v.w * inv;
        *(float4*)(q + c4 * 4) = r;
        qt[(size_t)(c4 * 4 + 0) << 12] = r.x;
        qt[(size_t)(c4 * 4 + 1) << 12] = r.y;
        qt[(size_t)(c4 * 4 + 2) << 12] = r.z;
        qt[(size_t)(c4 * 4 + 3) << 12] = r.w;
    }
}

// ---------------- EdgeConv 1: 6ch (channel-major x), 12->64->64, wave-per-point ----------------
__global__ __launch_bounds__(256) void k_edge1(const float* __restrict__ x,
    const float* __restrict__ w0, const float* __restrict__ s0, const float* __restrict__ o0,
    const float* __restrict__ w1, const float* __restrict__ s1, const float* __restrict__ o1,
    const int* __restrict__ idx, float* __restrict__ xcpm) {
    __shared__ float es[4][16];
    __shared__ float h0s[4][64];
    int t = threadIdx.x;
    int w = t >> 6, o = t & 63;
    int pid = blockIdx.x * 4 + w;
    int b = pid >> 12, n = pid & 4095;
    const float* xb = x + b * 6 * NPTS;
    float w0r[12];
    const float* w0p = w0 + o * 12;
#pragma unroll
    for (int c4 = 0; c4 < 3; c4++) {
        float4 v = *(const float4*)(w0p + c4 * 4);
        w0r[c4 * 4] = v.x; w0r[c4 * 4 + 1] = v.y; w0r[c4 * 4 + 2] = v.z; w0r[c4 * 4 + 3] = v.w;
    }
    float w1r[64];
    const float* w1p = w1 + o * 64;
#pragma unroll
    for (int c4 = 0; c4 < 16; c4++) {
        float4 v = *(const float4*)(w1p + c4 * 4);
        w1r[c4 * 4] = v.x; w1r[c4 * 4 + 1] = v.y; w1r[c4 * 4 + 2] = v.z; w1r[c4 * 4 + 3] = v.w;
    }
    float sv0 = s0[o], ov0 = o0[o], sv1 = s1[o], ov1 = o1[o];
    float cv = 0.f;
    if (o < 6) { cv = xb[o * NPTS + n]; es[w][6 + o] = cv; }
    if (o >= 12 && o < 16) es[w][o] = 0.f;
    float acc = -FLT_MAX;
    const int* ib = idx + pid * KNN;
    for (int kk = 0; kk < KNN; kk++) {
        int j = ib[kk] & 4095;
        if (o < 6) es[w][o] = xb[o * NPTS + j] - cv;
        float h = 0.f;
#pragma unroll
        for (int c4 = 0; c4 < 3; c4++) {
            float4 e4 = *(const float4*)&es[w][c4 * 4];
            h += w0r[c4 * 4] * e4.x + w0r[c4 * 4 + 1] * e4.y + w0r[c4 * 4 + 2] * e4.z + w0r[c4 * 4 + 3] * e4.w;
        }
        h = lrelu(h * sv0 + ov0);
        h0s[w][o] = h;
        float h2 = 0.f;
#pragma unroll
        for (int c4 = 0; c4 < 16; c4++) {
            float4 h4 = *(const float4*)&h0s[w][c4 * 4];
            h2 += w1r[c4 * 4] * h4.x + w1r[c4 * 4 + 1] * h4.y + w1r[c4 * 4 + 2] * h4.z + w1r[c4 * 4 + 3] * h4.w;
        }
        h2 = lrelu(h2 * sv1 + ov1);
        acc = fmaxf(acc, h2);
    }
    xcpm[(size_t)pid * 192 + o] = acc;
}

// ---------------- EdgeConv 2/3: point-major gather (pipelined), 128->64->64 ----------------
__global__ __launch_bounds__(256) void k_edge23(const float* __restrict__ xcpm,
    const float* __restrict__ w0, const float* __restrict__ s0, const float* __restrict__ o0,
    const float* __restrict__ w1, const float* __restrict__ s1, const float* __restrict__ o1,
    const int* __restrict__ idx, int ci, int co) {
    __shared__ float cs[4][64];
    __shared__ float es[4][64];
    __shared__ float h0s[4][64];
    int t = threadIdx.x;
    int w = t >> 6, o = t & 63;
    int pid = blockIdx.x * 4 + w;
    int b = pid >> 12;
    float w0r[64];
    const float* w0p = w0 + o * 128;
#pragma unroll
    for (int c4 = 0; c4 < 16; c4++) {
        float4 v = *(const float4*)(w0p + c4 * 4);
        w0r[c4 * 4] = v.x; w0r[c4 * 4 + 1] = v.y; w0r[c4 * 4 + 2] = v.z; w0r[c4 * 4 + 3] = v.w;
    }
    float w1r[64];
    const float* w1p = w1 + o * 64;
#pragma unroll
    for (int c4 = 0; c4 < 16; c4++) {
        float4 v = *(const float4*)(w1p + c4 * 4);
        w1r[c4 * 4] = v.x; w1r[c4 * 4 + 1] = v.y; w1r[c4 * 4 + 2] = v.z; w1r[c4 * 4 + 3] = v.w;
    }
    float sv0 = s0[o], ov0 = o0[o], sv1 = s1[o], ov1 = o1[o];
    float cv = xcpm[(size_t)pid * 192 + ci + o];
    cs[w][o] = cv;
    float h0b = 0.f;
    const float* w0q = w0p + 64;
#pragma unroll
    for (int c4 = 0; c4 < 16; c4++) {
        float4 wv = *(const float4*)(w0q + c4 * 4);
        float4 c4v = *(const float4*)&cs[w][c4 * 4];
        h0b += wv.x * c4v.x + wv.y * c4v.y + wv.z * c4v.z + wv.w * c4v.w;
    }
    float acc = -FLT_MAX;
    const int* ib = idx + pid * KNN;
    int j0 = ib[0] & 4095;
    float nv = xcpm[((size_t)(b * 4096 + j0)) * 192 + ci + o];
    for (int kk = 0; kk < KNN; kk++) {
        float cur = nv;
        if (kk < KNN - 1) {
            int jn = ib[kk + 1] & 4095;
            nv = xcpm[((size_t)(b * 4096 + jn)) * 192 + ci + o];
        }
        es[w][o] = cur - cv;
        float h = h0b;
#pragma unroll
        for (int c4 = 0; c4 < 16; c4++) {
            float4 e4 = *(const float4*)&es[w][c4 * 4];
            h += w0r[c4 * 4] * e4.x + w0r[c4 * 4 + 1] * e4.y + w0r[c4 * 4 + 2] * e4.z + w0r[c4 * 4 + 3] * e4.w;
        }
        h = lrelu(h * sv0 + ov0);
        h0s[w][o] = h;
        float h2 = 0.f;
#pragma unroll
        for (int c4 = 0; c4 < 16; c4++) {
            float4 h4 = *(const float4*)&h0s[w][c4 * 4];
            h2 += w1r[c4 * 4] * h4.x + w1r[c4 * 4 + 1] * h4.y + w1r[c4 * 4 + 2] * h4.z + w1r[c4 * 4 + 3] * h4.w;
        }
        h2 = lrelu(h2 * sv1 + ov1);
        acc = fmaxf(acc, h2);
    }
    float* outp = (float*)xcpm;
    outp[(size_t)pid * 192 + co + o] = acc;
}

// ---------------- init g to -inf ----------------
__global__ void k_init_g(float* __restrict__ g) {
    g[blockIdx.x * 256 + threadIdx.x] = -FLT_MAX;
}

// ---------------- w4+pool v2: outer-product 16o x 4tn, 64-pt staged tile, wT4 ----------------
__global__ __launch_bounds__(256) void k_w4pool(const float* __restrict__ xc,
                                                const float* __restrict__ wT4,
                                                const float* __restrict__ b4,
                                                float* __restrict__ g) {
    __shared__ float xcs[192 * 68];   // 64 points, stride 68 (52.2 KB)
    int t = threadIdx.x;
    int b = blockIdx.y;
    int n0 = blockIdx.x * 64;
    const float* xb = xc + (size_t)(b * 4096 + n0) * 192;
    for (int i = t; i < 3072; i += 256) {
        int pt = i / 48, c4 = i - pt * 48;
        float4 v = *(const float4*)(xb + pt * 192 + c4 * 4);
        xcs[(c4 * 4 + 0) * 68 + pt] = v.x; xcs[(c4 * 4 + 1) * 68 + pt] = v.y;
        xcs[(c4 * 4 + 2) * 68 + pt] = v.z; xcs[(c4 * 4 + 3) * 68 + pt] = v.w;
    }
    __syncthreads();
    int o0 = (t >> 2) * 16, qd = t & 3;
    float4 bb[4];
#pragma unroll
    for (int k = 0; k < 4; k++) bb[k] = *(const float4*)(b4 + o0 + k * 4);
    float mx[16];
#pragma unroll
    for (int oo = 0; oo < 16; oo++) mx[oo] = -FLT_MAX;
    for (int sub = 0; sub < 4; sub++) {
        int tn0 = sub * 16 + qd * 4;
        float4 acc[16];
#pragma unroll
        for (int oo = 0; oo < 16; oo++) acc[oo] = (float4){0, 0, 0, 0};
        for (int c = 0; c < 192; c++) {
            float4 x4 = *(const float4*)&xcs[c * 68 + tn0];
            const float* wr = wT4 + c * 1024 + o0;
            float4 wq[4];
#pragma unroll
            for (int k = 0; k < 4; k++) wq[k] = *(const float4*)(wr + k * 4);
#pragma unroll
            for (int oo = 0; oo < 16; oo++) {
                float wv = ((const float*)wq)[oo];
                acc[oo].x += wv * x4.x; acc[oo].y += wv * x4.y;
                acc[oo].z += wv * x4.z; acc[oo].w += wv * x4.w;
            }
        }
#pragma unroll
        for (int oo = 0; oo < 16; oo++) {
            float bias = ((const float*)bb)[oo];
            float4 a = acc[oo];
            float h = fmaxf(fmaxf(lrelu(a.x + bias), lrelu(a.y + bias)),
                            fmaxf(lrelu(a.z + bias), lrelu(a.w + bias)));
            mx[oo] = fmaxf(mx[oo], h);
        }
    }
#pragma unroll
    for (int oo = 0; oo < 16; oo++) {
        float v = mx[oo];
        v = fmaxf(v, __shfl_xor(v, 1));
        v = fmaxf(v, __shfl_xor(v, 2));
        if (qd == 0) atomicMaxF(&g[b * 1024 + o0 + oo], v);
    }
}

// ---------------- goff[b][o] = (wf1[o,192:1216] . g[b]) * sf1[o] + of1[o] ----------------
__global__ __launch_bounds__(256) void k_goff(const float* __restrict__ g,
                                              const float* __restrict__ wf1,
                                              const float* __restrict__ sf1,
                                              const float* __restrict__ of1,
                                              float* __restrict__ goff) {
    int bo = blockIdx.x;
    int b = bo >> 9, o = bo & 511;
    int t = threadIdx.x;
    const float* wr = wf1 + (size_t)o * 1216 + 192;
    const float* gb = g + b * 1024;
    float s = 0.f;
    for (int c = t; c < 1024; c += 256) s += wr[c] * gb[c];
    __shared__ float red[4];
    for (int off = 32; off > 0; off >>= 1) s += __shfl_down(s, off);
    if ((t & 63) == 0) red[t >> 6] = s;
    __syncthreads();
    if (t == 0) {
        float tot = red[0] + red[1] + red[2] + red[3];
        goff[bo] = tot * sf1[o] + of1[o];
    }
}

// ---------------- fused tail v2: outer-product register blocking, transposed weights ----------------
#define TP 20
__global__ __launch_bounds__(256) void k_tail(const float* __restrict__ xc,
                                              const float* __restrict__ wf1T,
                                              const float* __restrict__ sf1,
                                              const float* __restrict__ goff,
                                              const float* __restrict__ wf2T,
                                              const float* __restrict__ sf2,
                                              const float* __restrict__ of2,
                                              const float* __restrict__ wf3,
                                              float* __restrict__ out) {
    __shared__ float xcs[192 * TP];      // 15.4 KB
    __shared__ float h1s[512 * TP];      // 40 KB
    __shared__ float h2s[256 * TP];      // 20 KB
    int t = threadIdx.x;
    int b = blockIdx.y;
    int n0 = blockIdx.x * 16;
    const float* xb = xc + (size_t)(b * 4096 + n0) * 192;
    for (int i = t; i < 768; i += 256) {
        int pt = i / 48, c4 = i - pt * 48;
        float4 v = *(const float4*)(xb + pt * 192 + c4 * 4);
        xcs[(c4 * 4 + 0) * TP + pt] = v.x; xcs[(c4 * 4 + 1) * TP + pt] = v.y;
        xcs[(c4 * 4 + 2) * TP + pt] = v.z; xcs[(c4 * 4 + 3) * TP + pt] = v.w;
    }
    __syncthreads();
    // h1: thread = 8 outputs x 4 points
    {
        int o8 = (t >> 2) * 8, tn0 = (t & 3) * 4;
        float4 acc[8];
#pragma unroll
        for (int oo = 0; oo < 8; oo++) acc[oo] = (float4){0, 0, 0, 0};
        for (int c = 0; c < 192; c++) {
            float4 x4 = *(const float4*)&xcs[c * TP + tn0];
            const float* wr = wf1T + c * 512 + o8;
            float4 w0 = *(const float4*)(wr);
            float4 w1 = *(const float4*)(wr + 4);
            float wq[8] = {w0.x, w0.y, w0.z, w0.w, w1.x, w1.y, w1.z, w1.w};
#pragma unroll
            for (int oo = 0; oo < 8; oo++) {
                acc[oo].x += wq[oo] * x4.x; acc[oo].y += wq[oo] * x4.y;
                acc[oo].z += wq[oo] * x4.z; acc[oo].w += wq[oo] * x4.w;
            }
        }
#pragma unroll
        for (int oo = 0; oo < 8; oo++) {
            int o = o8 + oo;
            float s = sf1[o];
            float gv = goff[b * 512 + o];
            float4 r;
            r.x = lrelu(acc[oo].x * s + gv); r.y = lrelu(acc[oo].y * s + gv);
            r.z = lrelu(acc[oo].z * s + gv); r.w = lrelu(acc[oo].w * s + gv);
            *(float4*)&h1s[o * TP + tn0] = r;
        }
    }
    __syncthreads();
    // h2: thread = 4 outputs x 4 points
    {
        int o4 = (t >> 2) * 4, tn0 = (t & 3) * 4;
        float4 acc[4];
#pragma unroll
        for (int oo = 0; oo < 4; oo++) acc[oo] = (float4){0, 0, 0, 0};
        for (int c = 0; c < 512; c++) {
            float4 x4 = *(const float4*)&h1s[c * TP + tn0];
            float4 w = *(const float4*)(wf2T + c * 256 + o4);
            float wq[4] = {w.x, w.y, w.z, w.w};
#pragma unroll
            for (int oo = 0; oo < 4; oo++) {
                acc[oo].x += wq[oo] * x4.x; acc[oo].y += wq[oo] * x4.y;
                acc[oo].z += wq[oo] * x4.z; acc[oo].w += wq[oo] * x4.w;
            }
        }
#pragma unroll
        for (int oo = 0; oo < 4; oo++) {
            int o = o4 + oo;
            float s = sf2[o], of = of2[o];
            float4 r;
            r.x = lrelu(acc[oo].x * s + of); r.y = lrelu(acc[oo].y * s + of);
            r.z = lrelu(acc[oo].z * s + of); r.w = lrelu(acc[oo].w * s + of);
            *(float4*)&h2s[o * TP + tn0] = r;
        }
    }
    __syncthreads();
    // out: 13 x 16
    if (t < 13 * 16) {
        int o = t >> 4, tn = t & 15;
        const float* wr = wf3 + o * 256;
        float acc = 0.f;
        for (int c4 = 0; c4 < 64; c4++) {
            float4 wv = *(const float4*)(wr + c4 * 4);
            acc += wv.x * h2s[(c4 * 4 + 0) * TP + tn] + wv.y * h2s[(c4 * 4 + 1) * TP + tn]
                 + wv.z * h2s[(c4 * 4 + 2) * TP + tn] + wv.w * h2s[(c4 * 4 + 3) * TP + tn];
        }
        out[((size_t)b * 13 + o) * NPTS + n0 + tn] = acc;
    }
}

extern "C" void kernel_launch(void* const* d_in, const int* in_sizes, int n_in,
                              void* d_out, int out_size, void* d_ws, size_t ws_size,
                              hipStream_t stream) {
    const float* x    = (const float*)d_in[0];
    const float* w1_0 = (const float*)d_in[1];
    const float* s1_0 = (const float*)d_in[2];
    const float* o1_0 = (const float*)d_in[3];
    const float* w1_1 = (const float*)d_in[4];
    const float* s1_1 = (const float*)d_in[5];
    const float* o1_1 = (const float*)d_in[6];
    const float* w2_0 = (const float*)d_in[7];
    const float* s2_0 = (const float*)d_in[8];
    const float* o2_0 = (const float*)d_in[9];
    const float* w2_1 = (const float*)d_in[10];
    const float* s2_1 = (const float*)d_in[11];
    const float* o2_1 = (const float*)d_in[12];
    const float* w3_0 = (const float*)d_in[13];
    const float* s3_0 = (const float*)d_in[14];
    const float* o3_0 = (const float*)d_in[15];
    const float* w3_1 = (const float*)d_in[16];
    const float* s3_1 = (const float*)d_in[17];
    const float* o3_1 = (const float*)d_in[18];
    const float* w4   = (const float*)d_in[19];
    const float* b4   = (const float*)d_in[20];
    const float* wf1  = (const float*)d_in[21];
    const float* sf1  = (const float*)d_in[22];
    const float* of1  = (const float*)d_in[23];
    const float* wf2  = (const float*)d_in[24];
    const float* sf2  = (const float*)d_in[25];
    const float* of2  = (const float*)d_in[26];
    const float* wf3  = (const float*)d_in[27];
    // d_in[28] = k (int, always 20)

    // workspace layout (floats) — total ~24 MB
    float* xcpm = (float*)d_ws;                             // B*N*192 point-major
    float* xn   = xcpm + (size_t)NB * NPTS * 192;           // B*N*64 point-major
    float* sq   = xn + (size_t)NB * NPTS * 64;              // B*N
    float* g    = sq + NB * NPTS;                           // B*1024
    float* goff = g + NB * 1024;                            // B*512
    int*   idx  = (int*)(goff + NB * 512);                  // B*N*20
    float* wT4  = (float*)(idx + NB * NPTS * KNN);          // 192*1024
    float* wf1T = wT4 + 192 * 1024;                         // 192*512
    float* wf2T = wf1T + 192 * 512;                         // 512*256
    float* xnT  = wf2T + 512 * 256;                         // B*64*N channel-major
    (void)in_sizes; (void)n_in; (void)out_size; (void)ws_size;

    k_transp<<<(1024 * 192 + 255) / 256, 256, 0, stream>>>(w4, wT4, 1024, 192, 192);
    k_transp<<<(512 * 192 + 255) / 256, 256, 0, stream>>>(wf1, wf1T, 512, 1216, 192);
    k_transp<<<(256 * 512 + 255) / 256, 256, 0, stream>>>(wf2, wf2T, 256, 512, 512);
    k_sqnorm<<<NB * NPTS / 256, 256, 0, stream>>>(x, sq);
    k_knn_euclid<<<NB * NPTS / 4, 256, 0, stream>>>(x, sq, idx);
    k_edge1<<<NB * NPTS / 4, 256, 0, stream>>>(x, w1_0, s1_0, o1_0, w1_1, s1_1, o1_1, idx, xcpm);
    k_normalize<<<NB * NPTS / 256, 256, 0, stream>>>(xcpm, 0, xn, xnT);
    k_knn_cos<<<NB * NPTS / 8, 256, 0, stream>>>(xn, xnT, idx);
    k_edge23<<<NB * NPTS / 4, 256, 0, stream>>>(xcpm, w2_0, s2_0, o2_0, w2_1, s2_1, o2_1, idx, 0, 64);
    k_normalize<<<NB * NPTS / 256, 256, 0, stream>>>(xcpm, 64, xn, xnT);
    k_knn_cos<<<NB * NPTS / 8, 256, 0, stream>>>(xn, xnT, idx);
    k_edge23<<<NB * NPTS / 4, 256, 0, stream>>>(xcpm, w3_0, s3_0, o3_0, w3_1, s3_1, o3_1, idx, 64, 128);
    k_init_g<<<NB * 1024 / 256, 256, 0, stream>>>(g);
    k_w4pool<<<dim3(NPTS / 64, NB), 256, 0, stream>>>(xcpm, wT4, b4, g);
    k_goff<<<NB * 512, 256, 0, stream>>>(g, wf1, sf1, of1, goff);
    k_tail<<<dim3(NPTS / 16, NB), 256, 0, stream>>>(xcpm, wf1T, sf1, goff, wf2T, sf2, of2, wf3, (float*)d_out);
}

// Round 21
// 1520.418 us; speedup vs baseline: 1.1139x; 1.1139x over previous
//
#include <hip/hip_runtime.h>
#include <hip/hip_bf16.h>
#include <float.h>

#define NPTS 4096
#define NB 4
#define KNN 20

__device__ __forceinline__ float lrelu(float x) { return x > 0.f ? x : 0.2f * x; }

__device__ __forceinline__ void atomicMaxF(float* addr, float val) {
    int* ia = (int*)addr;
    int old = *ia;
    while (__int_as_float(old) < val) {
        int assumed = old;
        old = atomicCAS(ia, assumed, __float_as_int(val));
        if (old == assumed) break;
    }
}

// ---------------- generic transpose: dst[c][r] = src[r][c0..] ----------------
__global__ void k_transp(const float* __restrict__ src, float* __restrict__ dst,
                         int rows, int srcld, int cols) {
    int i = blockIdx.x * 256 + threadIdx.x;
    if (i >= rows * cols) return;
    int r = i % rows, c = i / rows;              // writes coalesced
    dst[c * rows + r] = src[(size_t)r * srcld + c];
}

// ---------------- sq norms for euclid knn ----------------
__global__ void k_sqnorm(const float* __restrict__ x, float* __restrict__ sq) {
    int i = blockIdx.x * 256 + threadIdx.x;   // b*N + n
    int b = i >> 12, n = i & 4095;
    const float* xb = x + b * 6 * NPTS;
    float s = 0.f;
#pragma unroll
    for (int c = 0; c < 6; c++) { float v = xb[c * NPTS + n]; s += v * v; }
    sq[i] = s;
}

// ---------------- euclid knn v3: streaming ballot top-20 on sv=-d, no LDS ----------------
__global__ __launch_bounds__(256) void k_knn_euclid(const float* __restrict__ x,
                                                    const float* __restrict__ sq,
                                                    int* __restrict__ idx) {
    int t = threadIdx.x;
    int w = t >> 6, ln = t & 63;
    int qid = blockIdx.x * 4 + w;
    int b = qid >> 12, qn = qid & 4095;
    const float* xb = x + b * 6 * NPTS;
    const float* sqb = sq + b * NPTS;
    float q0 = xb[qn], q1 = xb[NPTS + qn], q2 = xb[2 * NPTS + qn];
    float q3 = xb[3 * NPTS + qn], q4 = xb[4 * NPTS + qn], q5 = xb[5 * NPTS + qn];
    float sqn = sqb[qn];
    float lv = -FLT_MAX; int li = 0x7fffffff;
    float th = -FLT_MAX;
    for (int t0 = 0; t0 < NPTS; t0 += 64) {
        int m = t0 + ln;
        float dot = q0 * xb[m] + q1 * xb[NPTS + m] + q2 * xb[2 * NPTS + m]
                  + q3 * xb[3 * NPTS + m] + q4 * xb[4 * NPTS + m] + q5 * xb[5 * NPTS + m];
        float sv = -(sqn - 2.f * dot + sqb[m]);      // top-k of -d, exactly as reference
        unsigned long long mask = __ballot(sv > th);
        while (mask) {
            int src = __ffsll((unsigned long long)mask) - 1;
            mask &= mask - 1;
            float v = __shfl(sv, src);
            if (!(v > th)) continue;
            int mi = t0 + src;
            float pv = __shfl_up(lv, 1);
            int   pi = __shfl_up(li, 1);
            unsigned long long bm = __ballot(ln < 20 && lv >= v);
            int pos = __popcll(bm);
            if (ln < 20) {
                if (ln == pos) { lv = v; li = mi; }
                else if (ln > pos) { lv = pv; li = pi; }
            }
            th = __shfl(lv, 19);
        }
    }
    if (ln < KNN) idx[qid * KNN + ln] = li;
}

// ---------------- cosine knn v14: register GEMM + group pre-filter (measured-best R17) ----------------
__global__ __launch_bounds__(256) void k_knn_cos(const float* __restrict__ xn,
                                                 const float* __restrict__ xnT,
                                                 int* __restrict__ idx) {
    __shared__ float xq[64][20];         // [ch][q] (5.1 KB)
    __shared__ float simb[16][520];      // wave-private rows q=4w..4w+3 (33.3 KB)
    int t = threadIdx.x;
    int w = t >> 6, ln = t & 63;
    int b = blockIdx.x >> 8;             // 256 blocks per batch
    int q0blk = (blockIdx.x & 255) * 16;
    const float* xqg = xn + ((size_t)(b << 12) + q0blk) * 64;
    // stage 16 queries, transpose to [ch][q]
    {
        int q = t >> 4, c4 = t & 15;     // 256 float4, one per thread
        float4 v = *(const float4*)(xqg + q * 64 + c4 * 4);
        xq[c4 * 4 + 0][q] = v.x; xq[c4 * 4 + 1][q] = v.y;
        xq[c4 * 4 + 2][q] = v.z; xq[c4 * 4 + 3][q] = v.w;
    }
    __syncthreads();
    int myq = w * 4;
    const float* xTb = xnT + (((size_t)b) << 12) * 64;  // [c][4096]
    float lv[4] = {-FLT_MAX, -FLT_MAX, -FLT_MAX, -FLT_MAX};
    int   li[4] = {0x7fffffff, 0x7fffffff, 0x7fffffff, 0x7fffffff};
    float th[4] = {-FLT_MAX, -FLT_MAX, -FLT_MAX, -FLT_MAX};
    for (int strip = 0; strip < 8; strip++) {
        int m0 = strip * 512 + ln * 8;   // this lane's 8 candidates
        float4 a0[4], a1[4];
#pragma unroll
        for (int q = 0; q < 4; q++) { a0[q] = (float4){0,0,0,0}; a1[q] = (float4){0,0,0,0}; }
        for (int c = 0; c < 64; c++) {
            const float* cr = xTb + (((size_t)c) << 12) + m0;
            float4 cv0 = *(const float4*)(cr);
            float4 cv1 = *(const float4*)(cr + 4);
            float4 qv = *(const float4*)&xq[c][myq];   // wave-uniform broadcast
            a0[0].x += qv.x * cv0.x; a0[0].y += qv.x * cv0.y; a0[0].z += qv.x * cv0.z; a0[0].w += qv.x * cv0.w;
            a1[0].x += qv.x * cv1.x; a1[0].y += qv.x * cv1.y; a1[0].z += qv.x * cv1.z; a1[0].w += qv.x * cv1.w;
            a0[1].x += qv.y * cv0.x; a0[1].y += qv.y * cv0.y; a0[1].z += qv.y * cv0.z; a0[1].w += qv.y * cv0.w;
            a1[1].x += qv.y * cv1.x; a1[1].y += qv.y * cv1.y; a1[1].z += qv.y * cv1.z; a1[1].w += qv.y * cv1.w;
            a0[2].x += qv.z * cv0.x; a0[2].y += qv.z * cv0.y; a0[2].z += qv.z * cv0.z; a0[2].w += qv.z * cv0.w;
            a1[2].x += qv.z * cv1.x; a1[2].y += qv.z * cv1.y; a1[2].z += qv.z * cv1.z; a1[2].w += qv.z * cv1.w;
            a0[3].x += qv.w * cv0.x; a0[3].y += qv.w * cv0.y; a0[3].z += qv.w * cv0.z; a0[3].w += qv.w * cv0.w;
            a1[3].x += qv.w * cv1.x; a1[3].y += qv.w * cv1.y; a1[3].z += qv.w * cv1.z; a1[3].w += qv.w * cv1.w;
        }
        // per query: group pre-filter, conditional dump, filtered insertion passes
#pragma unroll
        for (int q = 0; q < 4; q++) {
            float mx8 = fmaxf(fmaxf(fmaxf(a0[q].x, a0[q].y), fmaxf(a0[q].z, a0[q].w)),
                              fmaxf(fmaxf(a1[q].x, a1[q].y), fmaxf(a1[q].z, a1[q].w)));
            unsigned long long gmask = __ballot(mx8 > th[q]);
            if (!gmask) continue;        // whole strip empty for this query
            *(float4*)&simb[myq + q][ln * 8] = a0[q];
            *(float4*)&simb[myq + q][ln * 8 + 4] = a1[q];
            for (int j = 0; j < 8; j++) {
                if (!((gmask >> (8 * j)) & 0xffull)) continue;   // group provably empty
                float sv = simb[myq + q][j * 64 + ln];
                int base = strip * 512 + j * 64;
                unsigned long long mask = __ballot(sv > th[q]);
                while (mask) {
                    int src = __ffsll((unsigned long long)mask) - 1;
                    mask &= mask - 1;
                    float v = __shfl(sv, src);
                    if (!(v > th[q])) continue;
                    int mi = base + src;
                    float pv = __shfl_up(lv[q], 1);
                    int   pi = __shfl_up(li[q], 1);
                    unsigned long long bm = __ballot(ln < 20 && lv[q] >= v);
                    int pos = __popcll(bm);
                    if (ln < 20) {
                        if (ln == pos) { lv[q] = v; li[q] = mi; }
                        else if (ln > pos) { lv[q] = pv; li[q] = pi; }
                    }
                    th[q] = __shfl(lv[q], 19);
                }
            }
        }
    }
#pragma unroll
    for (int q = 0; q < 4; q++) {
        if (ln < KNN) {
            int qid = (b << 12) + q0blk + myq + q;
            idx[(size_t)qid * KNN + ln] = li[q];
        }
    }
}

// ---------------- normalize 64 cols of point-major xcpm -> xn (point-major) + xnT (channel-major)
__global__ void k_normalize(const float* __restrict__ xcpm, int coff,
                            float* __restrict__ xn, float* __restrict__ xnT) {
    int pid = blockIdx.x * 256 + threadIdx.x;
    int b = pid >> 12, n = pid & 4095;
    const float* p = xcpm + (size_t)pid * 192 + coff;
    float s = 0.f;
#pragma unroll
    for (int c4 = 0; c4 < 16; c4++) {
        float4 v = *(const float4*)(p + c4 * 4);
        s += v.x * v.x + v.y * v.y + v.z * v.z + v.w * v.w;
    }
    float inv = 1.f / (sqrtf(s) + 1e-8f);
    float* q = xn + (size_t)pid * 64;
    float* qt = xnT + (((size_t)b) << 12) * 64 + n;
#pragma unroll
    for (int c4 = 0; c4 < 16; c4++) {
        float4 v = *(const float4*)(p + c4 * 4);
        float4 r; r.x = v.x * inv; r.y = v.y * inv; r.z = v.z * inv; r.w = v.w * inv;
        *(float4*)(q + c4 * 4) = r;
        qt[(size_t)(c4 * 4 + 0) << 12] = r.x;
        qt[(size_t)(c4 * 4 + 1) << 12] = r.y;
        qt[(size_t)(c4 * 4 + 2) << 12] = r.z;
        qt[(size_t)(c4 * 4 + 3) << 12] = r.w;
    }
}

// ---------------- EdgeConv 1: 6ch (channel-major x), 12->64->64, wave-per-point ----------------
__global__ __launch_bounds__(256) void k_edge1(const float* __restrict__ x,
    const float* __restrict__ w0, const float* __restrict__ s0, const float* __restrict__ o0,
    const float* __restrict__ w1, const float* __restrict__ s1, const float* __restrict__ o1,
    const int* __restrict__ idx, float* __restrict__ xcpm) {
    __shared__ float es[4][16];
    __shared__ float h0s[4][64];
    int t = threadIdx.x;
    int w = t >> 6, o = t & 63;
    int pid = blockIdx.x * 4 + w;
    int b = pid >> 12, n = pid & 4095;
    const float* xb = x + b * 6 * NPTS;
    float w0r[12];
    const float* w0p = w0 + o * 12;
#pragma unroll
    for (int c4 = 0; c4 < 3; c4++) {
        float4 v = *(const float4*)(w0p + c4 * 4);
        w0r[c4 * 4] = v.x; w0r[c4 * 4 + 1] = v.y; w0r[c4 * 4 + 2] = v.z; w0r[c4 * 4 + 3] = v.w;
    }
    float w1r[64];
    const float* w1p = w1 + o * 64;
#pragma unroll
    for (int c4 = 0; c4 < 16; c4++) {
        float4 v = *(const float4*)(w1p + c4 * 4);
        w1r[c4 * 4] = v.x; w1r[c4 * 4 + 1] = v.y; w1r[c4 * 4 + 2] = v.z; w1r[c4 * 4 + 3] = v.w;
    }
    float sv0 = s0[o], ov0 = o0[o], sv1 = s1[o], ov1 = o1[o];
    float cv = 0.f;
    if (o < 6) { cv = xb[o * NPTS + n]; es[w][6 + o] = cv; }
    if (o >= 12 && o < 16) es[w][o] = 0.f;
    float acc = -FLT_MAX;
    const int* ib = idx + pid * KNN;
    for (int kk = 0; kk < KNN; kk++) {
        int j = ib[kk] & 4095;
        if (o < 6) es[w][o] = xb[o * NPTS + j] - cv;
        float h = 0.f;
#pragma unroll
        for (int c4 = 0; c4 < 3; c4++) {
            float4 e4 = *(const float4*)&es[w][c4 * 4];
            h += w0r[c4 * 4] * e4.x + w0r[c4 * 4 + 1] * e4.y + w0r[c4 * 4 + 2] * e4.z + w0r[c4 * 4 + 3] * e4.w;
        }
        h = lrelu(h * sv0 + ov0);
        h0s[w][o] = h;
        float h2 = 0.f;
#pragma unroll
        for (int c4 = 0; c4 < 16; c4++) {
            float4 h4 = *(const float4*)&h0s[w][c4 * 4];
            h2 += w1r[c4 * 4] * h4.x + w1r[c4 * 4 + 1] * h4.y + w1r[c4 * 4 + 2] * h4.z + w1r[c4 * 4 + 3] * h4.w;
        }
        h2 = lrelu(h2 * sv1 + ov1);
        acc = fmaxf(acc, h2);
    }
    xcpm[(size_t)pid * 192 + o] = acc;
}

// ---------------- EdgeConv 2/3: point-major gather (pipelined), 128->64->64 ----------------
__global__ __launch_bounds__(256) void k_edge23(const float* __restrict__ xcpm,
    const float* __restrict__ w0, const float* __restrict__ s0, const float* __restrict__ o0,
    const float* __restrict__ w1, const float* __restrict__ s1, const float* __restrict__ o1,
    const int* __restrict__ idx, int ci, int co) {
    __shared__ float cs[4][64];
    __shared__ float es[4][64];
    __shared__ float h0s[4][64];
    int t = threadIdx.x;
    int w = t >> 6, o = t & 63;
    int pid = blockIdx.x * 4 + w;
    int b = pid >> 12;
    float w0r[64];
    const float* w0p = w0 + o * 128;
#pragma unroll
    for (int c4 = 0; c4 < 16; c4++) {
        float4 v = *(const float4*)(w0p + c4 * 4);
        w0r[c4 * 4] = v.x; w0r[c4 * 4 + 1] = v.y; w0r[c4 * 4 + 2] = v.z; w0r[c4 * 4 + 3] = v.w;
    }
    float w1r[64];
    const float* w1p = w1 + o * 64;
#pragma unroll
    for (int c4 = 0; c4 < 16; c4++) {
        float4 v = *(const float4*)(w1p + c4 * 4);
        w1r[c4 * 4] = v.x; w1r[c4 * 4 + 1] = v.y; w1r[c4 * 4 + 2] = v.z; w1r[c4 * 4 + 3] = v.w;
    }
    float sv0 = s0[o], ov0 = o0[o], sv1 = s1[o], ov1 = o1[o];
    float cv = xcpm[(size_t)pid * 192 + ci + o];
    cs[w][o] = cv;
    float h0b = 0.f;
    const float* w0q = w0p + 64;
#pragma unroll
    for (int c4 = 0; c4 < 16; c4++) {
        float4 wv = *(const float4*)(w0q + c4 * 4);
        float4 c4v = *(const float4*)&cs[w][c4 * 4];
        h0b += wv.x * c4v.x + wv.y * c4v.y + wv.z * c4v.z + wv.w * c4v.w;
    }
    float acc = -FLT_MAX;
    const int* ib = idx + pid * KNN;
    int j0 = ib[0] & 4095;
    float nv = xcpm[((size_t)(b * 4096 + j0)) * 192 + ci + o];
    for (int kk = 0; kk < KNN; kk++) {
        float cur = nv;
        if (kk < KNN - 1) {
            int jn = ib[kk + 1] & 4095;
            nv = xcpm[((size_t)(b * 4096 + jn)) * 192 + ci + o];
        }
        es[w][o] = cur - cv;
        float h = h0b;
#pragma unroll
        for (int c4 = 0; c4 < 16; c4++) {
            float4 e4 = *(const float4*)&es[w][c4 * 4];
            h += w0r[c4 * 4] * e4.x + w0r[c4 * 4 + 1] * e4.y + w0r[c4 * 4 + 2] * e4.z + w0r[c4 * 4 + 3] * e4.w;
        }
        h = lrelu(h * sv0 + ov0);
        h0s[w][o] = h;
        float h2 = 0.f;
#pragma unroll
        for (int c4 = 0; c4 < 16; c4++) {
            float4 h4 = *(const float4*)&h0s[w][c4 * 4];
            h2 += w1r[c4 * 4] * h4.x + w1r[c4 * 4 + 1] * h4.y + w1r[c4 * 4 + 2] * h4.z + w1r[c4 * 4 + 3] * h4.w;
        }
        h2 = lrelu(h2 * sv1 + ov1);
        acc = fmaxf(acc, h2);
    }
    float* outp = (float*)xcpm;
    outp[(size_t)pid * 192 + co + o] = acc;
}

// ---------------- init g to -inf ----------------
__global__ void k_init_g(float* __restrict__ g) {
    g[blockIdx.x * 256 + threadIdx.x] = -FLT_MAX;
}

// ---------------- w4+pool v2: outer-product 16o x 4tn, 64-pt staged tile, wT4 ----------------
__global__ __launch_bounds__(256) void k_w4pool(const float* __restrict__ xc,
                                                const float* __restrict__ wT4,
                                                const float* __restrict__ b4,
                                                float* __restrict__ g) {
    __shared__ float xcs[192 * 68];   // 64 points, stride 68 (52.2 KB)
    int t = threadIdx.x;
    int b = blockIdx.y;
    int n0 = blockIdx.x * 64;
    const float* xb = xc + (size_t)(b * 4096 + n0) * 192;
    for (int i = t; i < 3072; i += 256) {
        int pt = i / 48, c4 = i - pt * 48;
        float4 v = *(const float4*)(xb + pt * 192 + c4 * 4);
        xcs[(c4 * 4 + 0) * 68 + pt] = v.x; xcs[(c4 * 4 + 1) * 68 + pt] = v.y;
        xcs[(c4 * 4 + 2) * 68 + pt] = v.z; xcs[(c4 * 4 + 3) * 68 + pt] = v.w;
    }
    __syncthreads();
    int o0 = (t >> 2) * 16, qd = t & 3;
    float4 bb[4];
#pragma unroll
    for (int k = 0; k < 4; k++) bb[k] = *(const float4*)(b4 + o0 + k * 4);
    float mx[16];
#pragma unroll
    for (int oo = 0; oo < 16; oo++) mx[oo] = -FLT_MAX;
    for (int sub = 0; sub < 4; sub++) {
        int tn0 = sub * 16 + qd * 4;
        float4 acc[16];
#pragma unroll
        for (int oo = 0; oo < 16; oo++) acc[oo] = (float4){0, 0, 0, 0};
        for (int c = 0; c < 192; c++) {
            float4 x4 = *(const float4*)&xcs[c * 68 + tn0];
            const float* wr = wT4 + c * 1024 + o0;
            float4 wq[4];
#pragma unroll
            for (int k = 0; k < 4; k++) wq[k] = *(const float4*)(wr + k * 4);
#pragma unroll
            for (int oo = 0; oo < 16; oo++) {
                float wv = ((const float*)wq)[oo];
                acc[oo].x += wv * x4.x; acc[oo].y += wv * x4.y;
                acc[oo].z += wv * x4.z; acc[oo].w += wv * x4.w;
            }
        }
#pragma unroll
        for (int oo = 0; oo < 16; oo++) {
            float bias = ((const float*)bb)[oo];
            float4 a = acc[oo];
            float h = fmaxf(fmaxf(lrelu(a.x + bias), lrelu(a.y + bias)),
                            fmaxf(lrelu(a.z + bias), lrelu(a.w + bias)));
            mx[oo] = fmaxf(mx[oo], h);
        }
    }
#pragma unroll
    for (int oo = 0; oo < 16; oo++) {
        float v = mx[oo];
        v = fmaxf(v, __shfl_xor(v, 1));
        v = fmaxf(v, __shfl_xor(v, 2));
        if (qd == 0) atomicMaxF(&g[b * 1024 + o0 + oo], v);
    }
}

// ---------------- goff[b][o] = (wf1[o,192:1216] . g[b]) * sf1[o] + of1[o] ----------------
__global__ __launch_bounds__(256) void k_goff(const float* __restrict__ g,
                                              const float* __restrict__ wf1,
                                              const float* __restrict__ sf1,
                                              const float* __restrict__ of1,
                                              float* __restrict__ goff) {
    int bo = blockIdx.x;
    int b = bo >> 9, o = bo & 511;
    int t = threadIdx.x;
    const float* wr = wf1 + (size_t)o * 1216 + 192;
    const float* gb = g + b * 1024;
    float s = 0.f;
    for (int c = t; c < 1024; c += 256) s += wr[c] * gb[c];
    __shared__ float red[4];
    for (int off = 32; off > 0; off >>= 1) s += __shfl_down(s, off);
    if ((t & 63) == 0) red[t >> 6] = s;
    __syncthreads();
    if (t == 0) {
        float tot = red[0] + red[1] + red[2] + red[3];
        goff[bo] = tot * sf1[o] + of1[o];
    }
}

// ---------------- fused tail v2: outer-product register blocking, transposed weights ----------------
#define TP 20
__global__ __launch_bounds__(256) void k_tail(const float* __restrict__ xc,
                                              const float* __restrict__ wf1T,
                                              const float* __restrict__ sf1,
                                              const float* __restrict__ goff,
                                              const float* __restrict__ wf2T,
                                              const float* __restrict__ sf2,
                                              const float* __restrict__ of2,
                                              const float* __restrict__ wf3,
                                              float* __restrict__ out) {
    __shared__ float xcs[192 * TP];      // 15.4 KB
    __shared__ float h1s[512 * TP];      // 40 KB
    __shared__ float h2s[256 * TP];      // 20 KB
    int t = threadIdx.x;
    int b = blockIdx.y;
    int n0 = blockIdx.x * 16;
    const float* xb = xc + (size_t)(b * 4096 + n0) * 192;
    for (int i = t; i < 768; i += 256) {
        int pt = i / 48, c4 = i - pt * 48;
        float4 v = *(const float4*)(xb + pt * 192 + c4 * 4);
        xcs[(c4 * 4 + 0) * TP + pt] = v.x; xcs[(c4 * 4 + 1) * TP + pt] = v.y;
        xcs[(c4 * 4 + 2) * TP + pt] = v.z; xcs[(c4 * 4 + 3) * TP + pt] = v.w;
    }
    __syncthreads();
    // h1: thread = 8 outputs x 4 points
    {
        int o8 = (t >> 2) * 8, tn0 = (t & 3) * 4;
        float4 acc[8];
#pragma unroll
        for (int oo = 0; oo < 8; oo++) acc[oo] = (float4){0, 0, 0, 0};
        for (int c = 0; c < 192; c++) {
            float4 x4 = *(const float4*)&xcs[c * TP + tn0];
            const float* wr = wf1T + c * 512 + o8;
            float4 w0 = *(const float4*)(wr);
            float4 w1 = *(const float4*)(wr + 4);
            float wq[8] = {w0.x, w0.y, w0.z, w0.w, w1.x, w1.y, w1.z, w1.w};
#pragma unroll
            for (int oo = 0; oo < 8; oo++) {
                acc[oo].x += wq[oo] * x4.x; acc[oo].y += wq[oo] * x4.y;
                acc[oo].z += wq[oo] * x4.z; acc[oo].w += wq[oo] * x4.w;
            }
        }
#pragma unroll
        for (int oo = 0; oo < 8; oo++) {
            int o = o8 + oo;
            float s = sf1[o];
            float gv = goff[b * 512 + o];
            float4 r;
            r.x = lrelu(acc[oo].x * s + gv); r.y = lrelu(acc[oo].y * s + gv);
            r.z = lrelu(acc[oo].z * s + gv); r.w = lrelu(acc[oo].w * s + gv);
            *(float4*)&h1s[o * TP + tn0] = r;
        }
    }
    __syncthreads();
    // h2: thread = 4 outputs x 4 points
    {
        int o4 = (t >> 2) * 4, tn0 = (t & 3) * 4;
        float4 acc[4];
#pragma unroll
        for (int oo = 0; oo < 4; oo++) acc[oo] = (float4){0, 0, 0, 0};
        for (int c = 0; c < 512; c++) {
            float4 x4 = *(const float4*)&h1s[c * TP + tn0];
            float4 w = *(const float4*)(wf2T + c * 256 + o4);
            float wq[4] = {w.x, w.y, w.z, w.w};
#pragma unroll
            for (int oo = 0; oo < 4; oo++) {
                acc[oo].x += wq[oo] * x4.x; acc[oo].y += wq[oo] * x4.y;
                acc[oo].z += wq[oo] * x4.z; acc[oo].w += wq[oo] * x4.w;
            }
        }
#pragma unroll
        for (int oo = 0; oo < 4; oo++) {
            int o = o4 + oo;
            float s = sf2[o], of = of2[o];
            float4 r;
            r.x = lrelu(acc[oo].x * s + of); r.y = lrelu(acc[oo].y * s + of);
            r.z = lrelu(acc[oo].z * s + of); r.w = lrelu(acc[oo].w * s + of);
            *(float4*)&h2s[o * TP + tn0] = r;
        }
    }
    __syncthreads();
    // out: 13 x 16
    if (t < 13 * 16) {
        int o = t >> 4, tn = t & 15;
        const float* wr = wf3 + o * 256;
        float acc = 0.f;
        for (int c4 = 0; c4 < 64; c4++) {
            float4 wv = *(const float4*)(wr + c4 * 4);
            acc += wv.x * h2s[(c4 * 4 + 0) * TP + tn] + wv.y * h2s[(c4 * 4 + 1) * TP + tn]
                 + wv.z * h2s[(c4 * 4 + 2) * TP + tn] + wv.w * h2s[(c4 * 4 + 3) * TP + tn];
        }
        out[((size_t)b * 13 + o) * NPTS + n0 + tn] = acc;
    }
}

extern "C" void kernel_launch(void* const* d_in, const int* in_sizes, int n_in,
                              void* d_out, int out_size, void* d_ws, size_t ws_size,
                              hipStream_t stream) {
    const float* x    = (const float*)d_in[0];
    const float* w1_0 = (const float*)d_in[1];
    const float* s1_0 = (const float*)d_in[2];
    const float* o1_0 = (const float*)d_in[3];
    const float* w1_1 = (const float*)d_in[4];
    const float* s1_1 = (const float*)d_in[5];
    const float* o1_1 = (const float*)d_in[6];
    const float* w2_0 = (const float*)d_in[7];
    const float* s2_0 = (const float*)d_in[8];
    const float* o2_0 = (const float*)d_in[9];
    const float* w2_1 = (const float*)d_in[10];
    const float* s2_1 = (const float*)d_in[11];
    const float* o2_1 = (const float*)d_in[12];
    const float* w3_0 = (const float*)d_in[13];
    const float* s3_0 = (const float*)d_in[14];
    const float* o3_0 = (const float*)d_in[15];
    const float* w3_1 = (const float*)d_in[16];
    const float* s3_1 = (const float*)d_in[17];
    const float* o3_1 = (const float*)d_in[18];
    const float* w4   = (const float*)d_in[19];
    const float* b4   = (const float*)d_in[20];
    const float* wf1  = (const float*)d_in[21];
    const float* sf1  = (const float*)d_in[22];
    const float* of1  = (const float*)d_in[23];
    const float* wf2  = (const float*)d_in[24];
    const float* sf2  = (const float*)d_in[25];
    const float* of2  = (const float*)d_in[26];
    const float* wf3  = (const float*)d_in[27];
    // d_in[28] = k (int, always 20)

    // workspace layout (floats) — total ~24 MB
    float* xcpm = (float*)d_ws;                             // B*N*192 point-major
    float* xn   = xcpm + (size_t)NB * NPTS * 192;           // B*N*64 point-major
    float* sq   = xn + (size_t)NB * NPTS * 64;              // B*N
    float* g    = sq + NB * NPTS;                           // B*1024
    float* goff = g + NB * 1024;                            // B*512
    int*   idx  = (int*)(goff + NB * 512);                  // B*N*20
    float* wT4  = (float*)(idx + NB * NPTS * KNN);          // 192*1024
    float* wf1T = wT4 + 192 * 1024;                         // 192*512
    float* wf2T = wf1T + 192 * 512;                         // 512*256
    float* xnT  = wf2T + 512 * 256;                         // B*64*N channel-major
    (void)in_sizes; (void)n_in; (void)out_size; (void)ws_size;

    k_transp<<<(1024 * 192 + 255) / 256, 256, 0, stream>>>(w4, wT4, 1024, 192, 192);
    k_transp<<<(512 * 192 + 255) / 256, 256, 0, stream>>>(wf1, wf1T, 512, 1216, 192);
    k_transp<<<(256 * 512 + 255) / 256, 256, 0, stream>>>(wf2, wf2T, 256, 512, 512);
    k_sqnorm<<<NB * NPTS / 256, 256, 0, stream>>>(x, sq);
    k_knn_euclid<<<NB * NPTS / 4, 256, 0, stream>>>(x, sq, idx);
    k_edge1<<<NB * NPTS / 4, 256, 0, stream>>>(x, w1_0, s1_0, o1_0, w1_1, s1_1, o1_1, idx, xcpm);
    k_normalize<<<NB * NPTS / 256, 256, 0, stream>>>(xcpm, 0, xn, xnT);
    k_knn_cos<<<NB * NPTS / 16, 256, 0, stream>>>(xn, xnT, idx);
    k_edge23<<<NB * NPTS / 4, 256, 0, stream>>>(xcpm, w2_0, s2_0, o2_0, w2_1, s2_1, o2_1, idx, 0, 64);
    k_normalize<<<NB * NPTS / 256, 256, 0, stream>>>(xcpm, 64, xn, xnT);
    k_knn_cos<<<NB * NPTS / 16, 256, 0, stream>>>(xn, xnT, idx);
    k_edge23<<<NB * NPTS / 4, 256, 0, stream>>>(xcpm, w3_0, s3_0, o3_0, w3_1, s3_1, o3_1, idx, 64, 128);
    k_init_g<<<NB * 1024 / 256, 256, 0, stream>>>(g);
    k_w4pool<<<dim3(NPTS / 64, NB), 256, 0, stream>>>(xcpm, wT4, b4, g);
    k_goff<<<NB * 512, 256, 0, stream>>>(g, wf1, sf1, of1, goff);
    k_tail<<<dim3(NPTS / 16, NB), 256, 0, stream>>>(xcpm, wf1T, sf1, goff, wf2T, sf2, of2, wf3, (float*)d_out);
}